// Round 1
// 1930.478 us; speedup vs baseline: 1.0615x; 1.0615x over previous
//
#include <hip/hip_runtime.h>
#include <math.h>

#define NTRAJ 32
#define TLEN  64
#define BATCH (NTRAJ*TLEN)   // 2048

__device__ __forceinline__ float eluf(float x){ return x > 0.f ? x : expm1f(x); }
__device__ __forceinline__ float sigmf(float x){ return 1.f/(1.f+expf(-x)); }

// ---------------- conv1: NHWC (C=4) input -> 32 channel planes ----------------
__global__ __launch_bounds__(256) void conv1_kernel(
    const float* __restrict__ in,   // [2048][84][84][4]
    const float* __restrict__ w,    // [3][3][4][32] HWIO
    const float* __restrict__ b,    // [32]
    float* __restrict__ out)        // [32][2048*42*42]
{
    int pos = blockIdx.x*256 + threadIdx.x;      // 3,612,672 exactly
    int n   = pos / (42*42);
    int rem = pos % (42*42);
    int oy  = rem / 42, ox = rem % 42;
    float acc[32];
    #pragma unroll
    for(int o=0;o<32;o++) acc[o] = b[o];
    for(int ky=0; ky<3; ky++){
        int iy = 2*oy + ky;                      // pad_before = 0 (84->42 SAME)
        if(iy >= 84) continue;
        for(int kx=0; kx<3; kx++){
            int ix = 2*ox + kx;
            if(ix >= 84) continue;
            float4 v = *(const float4*)(in + (((n*84 + iy)*84) + ix)*4);
            const float* wq = w + (ky*3 + kx)*128;   // [ci][32]
            #pragma unroll
            for(int o=0;o<32;o++) acc[o] += v.x*wq[o];
            #pragma unroll
            for(int o=0;o<32;o++) acc[o] += v.y*wq[32+o];
            #pragma unroll
            for(int o=0;o<32;o++) acc[o] += v.z*wq[64+o];
            #pragma unroll
            for(int o=0;o<32;o++) acc[o] += v.w*wq[96+o];
        }
    }
    const int NPOS = BATCH*42*42;
    #pragma unroll
    for(int o=0;o<32;o++) out[o*NPOS + pos] = eluf(acc[o]);
}

// ---------------- conv2/3/4: 32 planes -> 32 planes ----------------
template<int IH, int IW, int OH, int OW, int PB>
__global__ __launch_bounds__(256) void convN_kernel(
    const float* __restrict__ in,   // [32][BATCH*IH*IW]
    const float* __restrict__ w,    // [3][3][32][32] HWIO
    const float* __restrict__ b,    // [32]
    float* __restrict__ out)        // [32][BATCH*OH*OW]
{
    const int IPLANE = BATCH*IH*IW;
    const int OPLANE = BATCH*OH*OW;
    int pos = blockIdx.x*256 + threadIdx.x;
    if(pos >= OPLANE) return;
    int n   = pos / (OH*OW);
    int rem = pos % (OH*OW);
    int oy  = rem / OW, ox = rem % OW;
    float acc[32];
    #pragma unroll
    for(int o=0;o<32;o++) acc[o] = b[o];
    for(int ky=0; ky<3; ky++){
        int iy = 2*oy + ky - PB;
        if(iy < 0 || iy >= IH) continue;
        for(int kx=0; kx<3; kx++){
            int ix = 2*ox + kx - PB;
            if(ix < 0 || ix >= IW) continue;
            const float* ip = in + (n*IH + iy)*IW + ix;
            const float* wp = w + (ky*3 + kx)*1024;  // [ci][32]
            for(int ci=0; ci<32; ci+=4){
                float x0 = ip[(ci+0)*IPLANE];
                float x1 = ip[(ci+1)*IPLANE];
                float x2 = ip[(ci+2)*IPLANE];
                float x3 = ip[(ci+3)*IPLANE];
                const float* wq = wp + ci*32;        // uniform -> s_load
                #pragma unroll
                for(int o=0;o<32;o++) acc[o] += x0*wq[o];
                #pragma unroll
                for(int o=0;o<32;o++) acc[o] += x1*wq[32+o];
                #pragma unroll
                for(int o=0;o<32;o++) acc[o] += x2*wq[64+o];
                #pragma unroll
                for(int o=0;o<32;o++) acc[o] += x3*wq[96+o];
            }
        }
    }
    #pragma unroll
    for(int o=0;o<32;o++) out[o*OPLANE + pos] = eluf(acc[o]);
}

// ---------------- conv4 planes -> A_T[feat=1152][row=2048], row = t*32+n ------
__global__ __launch_bounds__(256) void relayout_kernel(
    const float* __restrict__ p4,   // [32][2048*36]
    float* __restrict__ at)         // [1152][2048]
{
    int i = blockIdx.x*256 + threadIdx.x;   // 2,359,296 exactly
    int f = i >> 11, r = i & 2047;          // write coalesced over r
    int s = f >> 5,  c = f & 31;            // feat = (y*6+x)*32 + c, s = y*6+x
    int t = r >> 5,  n = r & 31;            // r = t*32 + n
    int nt = n*64 + t;
    at[i] = p4[c*(BATCH*36) + nt*36 + s];
}

// ---------------- gate pre-projection: gx[r][1024] = A_T^T @ Wx + b ----------
__global__ __launch_bounds__(256) void gx_gemm_kernel(
    const float* __restrict__ at,   // [1152][2048]
    const float* __restrict__ lw,   // [1408][1024] (rows 0..1151 = Wx)
    const float* __restrict__ lb,   // [1024]
    float* __restrict__ gx,         // [2048][1024], row r = t*32+n
    unsigned int* __restrict__ bar) // barrier counter for lstm_coop (zeroed here)
{
    if(blockIdx.x == 0 && blockIdx.y == 0 && threadIdx.x == 0) *bar = 0u;
    int lane = threadIdx.x & 63;
    int wv   = threadIdx.x >> 6;
    int r0   = blockIdx.x * 16;                    // grid.x = 128
    int oc   = blockIdx.y*256 + wv*64 + lane;      // grid.y = 4
    float acc[16];
    float bias = lb[oc];
    #pragma unroll
    for(int i=0;i<16;i++) acc[i] = bias;
    #pragma unroll 4
    for(int k=0;k<1152;k++){
        float wval = lw[k*1024 + oc];              // coalesced v-load
        const float* ap = at + k*2048 + r0;        // uniform -> s_load_dwordx16
        #pragma unroll
        for(int i=0;i<16;i++) acc[i] += ap[i] * wval;
    }
    #pragma unroll
    for(int i=0;i<16;i++) gx[(r0+i)*1024 + oc] = acc[i];  // coalesced
}

// ---------------- cooperative weight-stationary LSTM --------------------------
// 32 WGs x 256 threads. WG g owns units [8g, 8g+8): local col c = gate*8+uu,
// global col = gate*256 + g*8 + uu. Wh slice (256x32 = 32KB) lives in LDS for
// the whole kernel; per step only h (32KB) crosses WGs via global memory +
// one agent-scope barrier. Matvec tile: 4 trajs x 1 col per thread.
__global__ __launch_bounds__(256) void lstm_coop_kernel(
    const float* __restrict__ gx,   // [2048][1024], row = st*32+n (bias folded)
    const float* __restrict__ lw,   // [1408][1024]; rows 1152.. = Wh
    const float* __restrict__ c0,   // [32][256]
    const float* __restrict__ h0,   // [32][256]
    float* __restrict__ feats,      // [2048][256], row = n*64+st
    float* __restrict__ hbuf,       // [2][32][256] double-buffered h broadcast
    unsigned int* __restrict__ bar) // monotonic barrier counter (pre-zeroed)
{
    __shared__ float hs[32*256];    // 32KB staged h (all 32 trajs)
    __shared__ float wl2[32*256];   // 32KB Wh slice, [k2][c][2] pair-interleave
    float* const gl = hs;           // gate buffer [32][33] aliases hs (phased)

    const int wg = blockIdx.x;      // unit-slice owner
    const int t  = threadIdx.x;
    const int c    = t & 31;        // local gate column 0..31
    const int ngrp = t >> 3 >> 2;   // t>>5: traj group 0..7 (4 trajs each)
    const int gcol = (c>>3)*256 + wg*8 + (c&7);   // global gate column
    const float* wh = lw + 1152*1024;

    // ---- one-time: Wh slice -> LDS ([k2][32][2]: w(2k2,c),w(2k2+1,c) adjacent)
    #pragma unroll
    for(int i=0;i<32;i++){
        int e = t + 256*i;                  // 8192 elements
        int k = e >> 5, cc = e & 31;
        int gc = (cc>>3)*256 + wg*8 + (cc&7);
        wl2[(k>>1)*64 + cc*2 + (k&1)] = wh[k*1024 + gc];
    }
    // ---- persistent cell state: thread t owns (n = t>>3, uu = t&7)
    const int un = t >> 3, uu = t & 7;
    float cst = c0[un*256 + wg*8 + uu];

    const float2* wv  = (const float2*)wl2;
    float4* hs4 = (float4*)hs;

    for(int st=0; st<64; ++st){
        // ---- stage full h(t-1) into LDS (coalesced 16B/lane)
        const float4* hp4 = (const float4*)((st == 0) ? h0 : (hbuf + ((st&1)^1)*8192));
        #pragma unroll
        for(int i=0;i<8;i++){
            int q = t + 256*i;
            hs4[q] = hp4[q];
        }
        // issue gx loads early; consumed only after the matvec loop
        int rbase = st*32 + ngrp*4;
        float gx0 = gx[(rbase+0)*1024 + gcol];
        float gx1 = gx[(rbase+1)*1024 + gcol];
        float gx2 = gx[(rbase+2)*1024 + gcol];
        float gx3 = gx[(rbase+3)*1024 + gcol];
        __syncthreads();
        // ---- matvec: 4 trajs x 1 col; h reads broadcast, w reads conflict-free
        float a0 = 0.f, a1 = 0.f, a2 = 0.f, a3 = 0.f;
        const float4* h0r = hs4 + (ngrp*4+0)*64;
        const float4* h1r = hs4 + (ngrp*4+1)*64;
        const float4* h2r = hs4 + (ngrp*4+2)*64;
        const float4* h3r = hs4 + (ngrp*4+3)*64;
        #pragma unroll 4
        for(int k4=0;k4<64;k4++){
            float2 wa = wv[(2*k4+0)*32 + c];
            float2 wb = wv[(2*k4+1)*32 + c];
            float4 hv0 = h0r[k4], hv1 = h1r[k4], hv2 = h2r[k4], hv3 = h3r[k4];
            a0 += hv0.x*wa.x + hv0.y*wa.y + hv0.z*wb.x + hv0.w*wb.y;
            a1 += hv1.x*wa.x + hv1.y*wa.y + hv1.z*wb.x + hv1.w*wb.y;
            a2 += hv2.x*wa.x + hv2.y*wa.y + hv2.z*wb.x + hv2.w*wb.y;
            a3 += hv3.x*wa.x + hv3.y*wa.y + hv3.z*wb.x + hv3.w*wb.y;
        }
        __syncthreads();                    // hs reads done -> safe to alias gl
        gl[(ngrp*4+0)*33 + c] = a0 + gx0;
        gl[(ngrp*4+1)*33 + c] = a1 + gx1;
        gl[(ngrp*4+2)*33 + c] = a2 + gx2;
        gl[(ngrp*4+3)*33 + c] = a3 + gx3;
        __syncthreads();
        // ---- update: thread owns (un, uu); [32][33] pad -> conflict-free reads
        {
            float i_ = gl[un*33 +      uu];
            float j_ = gl[un*33 +  8 + uu];
            float f_ = gl[un*33 + 16 + uu];
            float o_ = gl[un*33 + 24 + uu];
            cst = cst*sigmf(f_ + 1.f) + sigmf(i_)*tanhf(j_);
            float h = tanhf(cst)*sigmf(o_);
            int col = wg*8 + uu;
            hbuf[(st&1)*8192 + un*256 + col] = h;
            feats[(un*64 + st)*256 + col]    = h;
        }
        // ---- device-scope barrier: release flushes L2, acquire invalidates
        if(st != 63){
            __syncthreads();                // drains vmcnt(0): h stores in L2
            if(t == 0){
                unsigned tgt = (unsigned)(st+1)*32u;
                __hip_atomic_fetch_add(bar, 1u, __ATOMIC_ACQ_REL, __HIP_MEMORY_SCOPE_AGENT);
                unsigned spins = 0;
                while(__hip_atomic_load(bar, __ATOMIC_ACQUIRE, __HIP_MEMORY_SCOPE_AGENT) < tgt){
                    __builtin_amdgcn_s_sleep(2);
                    if(++spins > 20000000u) break;   // failsafe: no hard hang
                }
            }
            __syncthreads();
        }
    }
}

// ---------------- final FC: logits[p][18] = feats[p] @ fc_w + fc_b ----------
__global__ __launch_bounds__(64) void fc_kernel(
    const float* __restrict__ feats, const float* __restrict__ fw,
    const float* __restrict__ fb,    float* __restrict__ out)
{
    __shared__ float h[256];
    int p = blockIdx.x, t = threadIdx.x;
    *(float4*)&h[t*4] = *(const float4*)(feats + p*256 + t*4);
    __syncthreads();
    if(t < 18){
        float acc = fb[t];
        for(int k=0;k<256;k++) acc += h[k]*fw[k*18 + t];
        out[p*18 + t] = acc;
    }
}

extern "C" void kernel_launch(void* const* d_in, const int* in_sizes, int n_in,
                              void* d_out, int out_size, void* d_ws, size_t ws_size,
                              hipStream_t stream) {
    const float* inp = (const float*)d_in[0];
    const float* w1  = (const float*)d_in[1];  const float* b1 = (const float*)d_in[2];
    const float* w2  = (const float*)d_in[3];  const float* b2 = (const float*)d_in[4];
    const float* w3  = (const float*)d_in[5];  const float* b3 = (const float*)d_in[6];
    const float* w4  = (const float*)d_in[7];  const float* b4 = (const float*)d_in[8];
    const float* lw  = (const float*)d_in[9];  const float* lb = (const float*)d_in[10];
    const float* fw  = (const float*)d_in[11]; const float* fb = (const float*)d_in[12];
    const float* c0  = (const float*)d_in[13]; const float* h0 = (const float*)d_in[14];
    float* out = (float*)d_out;
    float* ws  = (float*)d_ws;

    const size_t n1 = (size_t)32*3612672;   // conv1 out planes
    const size_t n3 = (size_t)32*247808;    // conv3 out planes
    const size_t n4 = (size_t)32*73728;     // conv4 out planes

    float* p1 = ws;
    float* p2 = p1 + n1;                    // conv2 out (28.9M floats)
    float* p3 = ws;                         // reuse p1 region (conv3 reads only p2)
    float* p4 = p3 + n3;
    float* at = p4 + n4;                    // [1152][2048]
    float* gxb   = at  + (size_t)1152*2048; // [2048][1024]
    float* feats = gxb + (size_t)2048*1024; // [2048][256]
    float* hbuf  = feats + (size_t)2048*256;          // [2][32][256]
    unsigned int* bar = (unsigned int*)(hbuf + 2*32*256);

    conv1_kernel<<<14112,256,0,stream>>>(inp, w1, b1, p1);
    convN_kernel<42,42,21,21,0><<<3528,256,0,stream>>>(p1, w2, b2, p2);
    convN_kernel<21,21,11,11,1><<<968,256,0,stream>>>(p2, w3, b3, p3);
    convN_kernel<11,11, 6, 6,1><<<288,256,0,stream>>>(p3, w4, b4, p4);
    relayout_kernel<<<9216,256,0,stream>>>(p4, at);
    gx_gemm_kernel<<<dim3(128,4),256,0,stream>>>(at, lw, lb, gxb, bar);
    lstm_coop_kernel<<<32,256,0,stream>>>(gxb, lw, c0, h0, feats, hbuf, bar);
    fc_kernel<<<2048,64,0,stream>>>(feats, fw, fb, out);
}

// Round 2
// 1843.032 us; speedup vs baseline: 1.1118x; 1.0474x over previous
//
#include <hip/hip_runtime.h>
#include <math.h>

#define NTRAJ 32
#define TLEN  64
#define BATCH (NTRAJ*TLEN)   // 2048

__device__ __forceinline__ float eluf(float x){ return x > 0.f ? x : expm1f(x); }
__device__ __forceinline__ float sigmf(float x){ return 1.f/(1.f+expf(-x)); }

// ---------------- conv1: NHWC (C=4) input -> NHWC [2048][42][42][32] ----------
__global__ __launch_bounds__(256) void conv1_kernel(
    const float* __restrict__ in,   // [2048][84][84][4]
    const float* __restrict__ w,    // [3][3][4][32] HWIO
    const float* __restrict__ b,    // [32]
    float* __restrict__ out)        // [2048][42][42][32]
{
    int bid = blockIdx.x;
    bid = (bid & 7)*1764 + (bid >> 3);           // XCD chunk swizzle (14112%8==0)
    int pos = bid*256 + threadIdx.x;             // 3,612,672 exactly
    int n   = pos / (42*42);
    int rem = pos % (42*42);
    int oy  = rem / 42, ox = rem % 42;
    float acc[32];
    #pragma unroll
    for(int o=0;o<32;o++) acc[o] = b[o];
    for(int ky=0; ky<3; ky++){
        int iy = 2*oy + ky;                      // pad_before = 0 (84->42 SAME)
        if(iy >= 84) continue;
        for(int kx=0; kx<3; kx++){
            int ix = 2*ox + kx;
            if(ix >= 84) continue;
            float4 v = *(const float4*)(in + (((n*84 + iy)*84) + ix)*4);
            const float* wq = w + (ky*3 + kx)*128;   // [ci][32]
            #pragma unroll
            for(int o=0;o<32;o++) acc[o] += v.x*wq[o];
            #pragma unroll
            for(int o=0;o<32;o++) acc[o] += v.y*wq[32+o];
            #pragma unroll
            for(int o=0;o<32;o++) acc[o] += v.z*wq[64+o];
            #pragma unroll
            for(int o=0;o<32;o++) acc[o] += v.w*wq[96+o];
        }
    }
    float4* op = (float4*)(out + (size_t)pos*32);
    #pragma unroll
    for(int q=0;q<8;q++)
        op[q] = make_float4(eluf(acc[4*q]), eluf(acc[4*q+1]),
                            eluf(acc[4*q+2]), eluf(acc[4*q+3]));
}

// ---------------- conv2/3/4: NHWC 32ch -> NHWC 32ch ---------------------------
// Every fetched byte is used: tap = 8 contiguous float4 loads per lane.
template<int IH, int IW, int OH, int OW, int PB>
__global__ __launch_bounds__(256) void convN_kernel(
    const float* __restrict__ in,   // [BATCH][IH][IW][32]
    const float* __restrict__ w,    // [3][3][32][32] HWIO
    const float* __restrict__ b,    // [32]
    float* __restrict__ out)        // [BATCH][OH][OW][32]
{
    int bid = blockIdx.x;
    const int cpx = gridDim.x >> 3;              // all conv grids %8 == 0
    bid = (bid & 7)*cpx + (bid >> 3);            // XCD chunk swizzle
    int pos = bid*256 + threadIdx.x;
    if(pos >= BATCH*OH*OW) return;
    int n   = pos / (OH*OW);
    int rem = pos % (OH*OW);
    int oy  = rem / OW, ox = rem % OW;
    float acc[32];
    #pragma unroll
    for(int o=0;o<32;o++) acc[o] = b[o];
    for(int ky=0; ky<3; ky++){
        int iy = 2*oy + ky - PB;
        if(iy < 0 || iy >= IH) continue;
        for(int kx=0; kx<3; kx++){
            int ix = 2*ox + kx - PB;
            if(ix < 0 || ix >= IW) continue;
            const float4* ip = (const float4*)(in + ((size_t)(n*IH + iy)*IW + ix)*32);
            const float* wp = w + (ky*3 + kx)*1024;  // [ci][32]
            #pragma unroll
            for(int c4=0;c4<8;c4++){
                float4 x = ip[c4];
                const float* wq = wp + c4*128;       // uniform -> s_load
                #pragma unroll
                for(int o=0;o<32;o++) acc[o] += x.x*wq[o];
                #pragma unroll
                for(int o=0;o<32;o++) acc[o] += x.y*wq[32+o];
                #pragma unroll
                for(int o=0;o<32;o++) acc[o] += x.z*wq[64+o];
                #pragma unroll
                for(int o=0;o<32;o++) acc[o] += x.w*wq[96+o];
            }
        }
    }
    float4* op = (float4*)(out + (size_t)pos*32);
    #pragma unroll
    for(int q=0;q<8;q++)
        op[q] = make_float4(eluf(acc[4*q]), eluf(acc[4*q+1]),
                            eluf(acc[4*q+2]), eluf(acc[4*q+3]));
}

// ---------------- conv4 NHWC ([nt][feat]) -> A_T[feat=1152][row=2048] ---------
__global__ __launch_bounds__(256) void relayout_kernel(
    const float* __restrict__ p4,   // [2048(nt)][1152(f)]  (f = (y*6+x)*32 + c)
    float* __restrict__ at)         // [1152][2048], row r = t*32+n
{
    int i = blockIdx.x*256 + threadIdx.x;   // 2,359,296 exactly
    int f = i >> 11, r = i & 2047;          // write coalesced over r
    int tt = r >> 5, n = r & 31;            // r = t*32 + n
    int nt = n*64 + tt;
    at[i] = p4[nt*1152 + f];
}

// ---------------- gate pre-projection: gx[r][1024] = A_T^T @ Wx + b ----------
__global__ __launch_bounds__(256) void gx_gemm_kernel(
    const float* __restrict__ at,   // [1152][2048]
    const float* __restrict__ lw,   // [1408][1024] (rows 0..1151 = Wx)
    const float* __restrict__ lb,   // [1024]
    float* __restrict__ gx,         // [2048][1024], row r = t*32+n
    unsigned int* __restrict__ bar) // 32 flag words (stride 32) for lstm_coop
{
    if(blockIdx.x == 0 && blockIdx.y == 0 && threadIdx.x < 32)
        bar[threadIdx.x*32] = 0u;
    int lane = threadIdx.x & 63;
    int wv   = threadIdx.x >> 6;
    int r0   = blockIdx.x * 16;                    // grid.x = 128
    int oc   = blockIdx.y*256 + wv*64 + lane;      // grid.y = 4
    float acc[16];
    float bias = lb[oc];
    #pragma unroll
    for(int i=0;i<16;i++) acc[i] = bias;
    #pragma unroll 4
    for(int k=0;k<1152;k++){
        float wval = lw[k*1024 + oc];              // coalesced v-load
        const float* ap = at + k*2048 + r0;        // uniform -> s_load_dwordx16
        #pragma unroll
        for(int i=0;i<16;i++) acc[i] += ap[i] * wval;
    }
    #pragma unroll
    for(int i=0;i<16;i++) gx[(r0+i)*1024 + oc] = acc[i];  // coalesced
}

// ---------------- cooperative weight-stationary LSTM --------------------------
// 32 WGs x 256 threads, WG g owns units [8g,8g+8). Wh slice LDS-resident.
// Cross-WG sync: per-WG flag word on its own cache line (release store) +
// 32 parallel acquire polls -- no contended RMW serialization.
__global__ __launch_bounds__(256) void lstm_coop_kernel(
    const float* __restrict__ gx,   // [2048][1024], row = st*32+n (bias folded)
    const float* __restrict__ lw,   // [1408][1024]; rows 1152.. = Wh
    const float* __restrict__ c0,   // [32][256]
    const float* __restrict__ h0,   // [32][256]
    float* __restrict__ feats,      // [2048][256], row = n*64+st
    float* __restrict__ hbuf,       // [2][32][256] double-buffered h broadcast
    unsigned int* __restrict__ bar) // [32] flags, stride 32 uints (pre-zeroed)
{
    __shared__ float hs[32*256];    // 32KB staged h (all 32 trajs)
    __shared__ float wl2[32*256];   // 32KB Wh slice, [k2][c][2] pair-interleave
    float* const gl = hs;           // gate buffer [32][33] aliases hs (phased)

    const int wg = blockIdx.x;      // unit-slice owner
    const int t  = threadIdx.x;
    const int c    = t & 31;        // local gate column 0..31
    const int ngrp = t >> 5;        // traj group 0..7 (4 trajs each)
    const int gcol = (c>>3)*256 + wg*8 + (c&7);   // global gate column
    const float* wh = lw + 1152*1024;

    // ---- one-time: Wh slice -> LDS ([k2][32][2]: w(2k2,c),w(2k2+1,c) adjacent)
    #pragma unroll
    for(int i=0;i<32;i++){
        int e = t + 256*i;                  // 8192 elements
        int k = e >> 5, cc = e & 31;
        int gc = (cc>>3)*256 + wg*8 + (cc&7);
        wl2[(k>>1)*64 + cc*2 + (k&1)] = wh[k*1024 + gc];
    }
    // ---- persistent cell state: thread t owns (n = t>>3, uu = t&7)
    const int un = t >> 3, uu = t & 7;
    float cst = c0[un*256 + wg*8 + uu];

    const float2* wv  = (const float2*)wl2;
    float4* hs4 = (float4*)hs;

    for(int st=0; st<64; ++st){
        // ---- stage full h(t-1) into LDS (coalesced 16B/lane)
        const float4* hp4 = (const float4*)((st == 0) ? h0 : (hbuf + ((st&1)^1)*8192));
        #pragma unroll
        for(int i=0;i<8;i++){
            int q = t + 256*i;
            hs4[q] = hp4[q];
        }
        // issue gx loads early; consumed only after the matvec loop
        int rbase = st*32 + ngrp*4;
        float gx0 = gx[(rbase+0)*1024 + gcol];
        float gx1 = gx[(rbase+1)*1024 + gcol];
        float gx2 = gx[(rbase+2)*1024 + gcol];
        float gx3 = gx[(rbase+3)*1024 + gcol];
        __syncthreads();
        // ---- matvec: 4 trajs x 1 col; h reads broadcast, w reads conflict-free
        float a0 = 0.f, a1 = 0.f, a2 = 0.f, a3 = 0.f;
        const float4* h0r = hs4 + (ngrp*4+0)*64;
        const float4* h1r = hs4 + (ngrp*4+1)*64;
        const float4* h2r = hs4 + (ngrp*4+2)*64;
        const float4* h3r = hs4 + (ngrp*4+3)*64;
        #pragma unroll 4
        for(int k4=0;k4<64;k4++){
            float2 wa = wv[(2*k4+0)*32 + c];
            float2 wb = wv[(2*k4+1)*32 + c];
            float4 hv0 = h0r[k4], hv1 = h1r[k4], hv2 = h2r[k4], hv3 = h3r[k4];
            a0 += hv0.x*wa.x + hv0.y*wa.y + hv0.z*wb.x + hv0.w*wb.y;
            a1 += hv1.x*wa.x + hv1.y*wa.y + hv1.z*wb.x + hv1.w*wb.y;
            a2 += hv2.x*wa.x + hv2.y*wa.y + hv2.z*wb.x + hv2.w*wb.y;
            a3 += hv3.x*wa.x + hv3.y*wa.y + hv3.z*wb.x + hv3.w*wb.y;
        }
        __syncthreads();                    // hs reads done -> safe to alias gl
        gl[(ngrp*4+0)*33 + c] = a0 + gx0;
        gl[(ngrp*4+1)*33 + c] = a1 + gx1;
        gl[(ngrp*4+2)*33 + c] = a2 + gx2;
        gl[(ngrp*4+3)*33 + c] = a3 + gx3;
        __syncthreads();
        // ---- update: thread owns (un, uu); [32][33] pad -> conflict-free reads
        {
            float i_ = gl[un*33 +      uu];
            float j_ = gl[un*33 +  8 + uu];
            float f_ = gl[un*33 + 16 + uu];
            float o_ = gl[un*33 + 24 + uu];
            cst = cst*sigmf(f_ + 1.f) + sigmf(i_)*tanhf(j_);
            float h = tanhf(cst)*sigmf(o_);
            int col = wg*8 + uu;
            hbuf[(st&1)*8192 + un*256 + col] = h;
            feats[(un*64 + st)*256 + col]    = h;
        }
        // ---- distributed device barrier: own-flag release, parallel polls
        if(st != 63){
            __syncthreads();                // all h stores vmcnt-drained to L2
            if(t == 0)
                __hip_atomic_store(bar + wg*32, (unsigned)(st+1),
                                   __ATOMIC_RELEASE, __HIP_MEMORY_SCOPE_AGENT);
            if(t < 32){
                unsigned tgt = (unsigned)(st+1);
                unsigned spins = 0;
                while(__hip_atomic_load(bar + t*32, __ATOMIC_ACQUIRE,
                                        __HIP_MEMORY_SCOPE_AGENT) < tgt){
                    __builtin_amdgcn_s_sleep(1);
                    if(++spins > 20000000u) break;   // failsafe: no hard hang
                }
            }
            __syncthreads();
        }
    }
}

// ---------------- final FC: logits[p][18] = feats[p] @ fc_w + fc_b ----------
__global__ __launch_bounds__(64) void fc_kernel(
    const float* __restrict__ feats, const float* __restrict__ fw,
    const float* __restrict__ fb,    float* __restrict__ out)
{
    __shared__ float h[256];
    int p = blockIdx.x, t = threadIdx.x;
    *(float4*)&h[t*4] = *(const float4*)(feats + p*256 + t*4);
    __syncthreads();
    if(t < 18){
        float acc = fb[t];
        for(int k=0;k<256;k++) acc += h[k]*fw[k*18 + t];
        out[p*18 + t] = acc;
    }
}

extern "C" void kernel_launch(void* const* d_in, const int* in_sizes, int n_in,
                              void* d_out, int out_size, void* d_ws, size_t ws_size,
                              hipStream_t stream) {
    const float* inp = (const float*)d_in[0];
    const float* w1  = (const float*)d_in[1];  const float* b1 = (const float*)d_in[2];
    const float* w2  = (const float*)d_in[3];  const float* b2 = (const float*)d_in[4];
    const float* w3  = (const float*)d_in[5];  const float* b3 = (const float*)d_in[6];
    const float* w4  = (const float*)d_in[7];  const float* b4 = (const float*)d_in[8];
    const float* lw  = (const float*)d_in[9];  const float* lb = (const float*)d_in[10];
    const float* fw  = (const float*)d_in[11]; const float* fb = (const float*)d_in[12];
    const float* c0  = (const float*)d_in[13]; const float* h0 = (const float*)d_in[14];
    float* out = (float*)d_out;
    float* ws  = (float*)d_ws;

    const size_t n1 = (size_t)32*3612672;   // conv1 out (NHWC, same float count)
    const size_t n3 = (size_t)32*247808;    // conv3 out
    const size_t n4 = (size_t)32*73728;     // conv4 out

    float* p1 = ws;
    float* p2 = p1 + n1;                    // conv2 out (28.9M floats)
    float* p3 = ws;                         // reuse p1 region (conv3 reads only p2)
    float* p4 = p3 + n3;
    float* at = p4 + n4;                    // [1152][2048]
    float* gxb   = at  + (size_t)1152*2048; // [2048][1024]
    float* feats = gxb + (size_t)2048*1024; // [2048][256]
    float* hbuf  = feats + (size_t)2048*256;          // [2][32][256]
    unsigned int* bar = (unsigned int*)(hbuf + 2*32*256);  // [32] stride-32 flags

    conv1_kernel<<<14112,256,0,stream>>>(inp, w1, b1, p1);
    convN_kernel<42,42,21,21,0><<<3528,256,0,stream>>>(p1, w2, b2, p2);
    convN_kernel<21,21,11,11,1><<<968,256,0,stream>>>(p2, w3, b3, p3);
    convN_kernel<11,11, 6, 6,1><<<288,256,0,stream>>>(p3, w4, b4, p4);
    relayout_kernel<<<9216,256,0,stream>>>(p4, at);
    gx_gemm_kernel<<<dim3(128,4),256,0,stream>>>(at, lw, lb, gxb, bar);
    lstm_coop_kernel<<<32,256,0,stream>>>(gxb, lw, c0, h0, feats, hbuf, bar);
    fc_kernel<<<2048,64,0,stream>>>(feats, fw, fb, out);
}